// Round 2
// baseline (2016.880 us; speedup 1.0000x reference)
//
#include <hip/hip_runtime.h>
#include <hip/hip_bf16.h>

#define IGNORE_INDEX (-100)
#define BETA 0.1f

typedef __bf16 bf16x8 __attribute__((ext_vector_type(8)));
typedef float  f32x16 __attribute__((ext_vector_type(16)));

__device__ __forceinline__ void gload_lds16(const void* g, void* l) {
  __builtin_amdgcn_global_load_lds((const __attribute__((address_space(1))) void*)g,
                                   (__attribute__((address_space(3))) void*)l, 16, 0, 0);
}

__device__ __forceinline__ unsigned short f2bf(float f) {
  __hip_bfloat16 h = __float2bfloat16(f);
  return __builtin_bit_cast(unsigned short, h);
}

#define PH_BARRIER()  __builtin_amdgcn_s_barrier()
#define LGKM0()       asm volatile("s_waitcnt lgkmcnt(0)" ::: "memory")
#define VMCNT(N)      asm volatile("s_waitcnt vmcnt(" #N ")" ::: "memory")
#define SCHED_FENCE() __builtin_amdgcn_sched_barrier(0)
#define PRIO1()       __builtin_amdgcn_s_setprio(1)
#define PRIO0()       __builtin_amdgcn_s_setprio(0)

// ---------------- cast fp32 -> bf16, 8 elems/thread ----------------
__global__ void cast_f32_bf16_k(const float* __restrict__ src,
                                unsigned short* __restrict__ dst, long long n) {
  long long i = (long long)blockIdx.x * blockDim.x + threadIdx.x;
  long long b = i * 8;
  if (b + 8 > n) return;
  const float4* s4 = (const float4*)(src + b);
  float4 a = s4[0], c = s4[1];
  uint4 o;
  o.x = (unsigned)f2bf(a.x) | ((unsigned)f2bf(a.y) << 16);
  o.y = (unsigned)f2bf(a.z) | ((unsigned)f2bf(a.w) << 16);
  o.z = (unsigned)f2bf(c.x) | ((unsigned)f2bf(c.y) << 16);
  o.w = (unsigned)f2bf(c.z) | ((unsigned)f2bf(c.w) << 16);
  *(uint4*)(dst + b) = o;
}

// ---------------- 256x256 8-phase GEMM (32x32x16 MFMA) + per-vtile LSE ----------
// A: bf16 [4096][2048], B: bf16 [32000][2048] (NT). BK=64, 8 waves (2Mx4N),
// wave tile 128x64 = 4 mfrag x 2 nfrag of 32x32, 4 k-steps of 16.
// LDS layout (per 32KB region): addr(r,cs) = (r>>3)*1024 + cs*128 + (r&7)*16
//   (cs = 16B k-chunk 0..7). Makes 32x32 operand reads affine: base + mf*4096
//   + ks*256, bank-quad = lane&7 -> conflict-free. Stage dest stays lane-linear;
//   per-lane SOURCE map: row = w*16 + j*8 + (lane&7), chunk = lane>>3 (same
//   8-row x 128B coalescing as before, no XOR needed).
// Schedule identical to round 1 (stage slots, VMCNT(6) at P4/P8).

__device__ __forceinline__ void ld_a32(bf16x8 (&af)[4], const char* pa) {
#pragma unroll
  for (int ks = 0; ks < 4; ks++) af[ks] = *(const bf16x8*)(pa + ks * 256);
}

__device__ __forceinline__ void ld_b32(bf16x8 (&b)[2][4], const char* pb) {
#pragma unroll
  for (int nf = 0; nf < 2; nf++)
#pragma unroll
    for (int ks = 0; ks < 4; ks++)
      b[nf][ks] = *(const bf16x8*)(pb + nf * 4096 + ks * 256);
}

__device__ __forceinline__ void mfma_ph(f32x16& c0, f32x16& c1,
                                        const bf16x8 (&a)[4], const bf16x8 (&b)[2][4]) {
#pragma unroll
  for (int ks = 0; ks < 4; ks++) {
    c0 = __builtin_amdgcn_mfma_f32_32x32x16_bf16(a[ks], b[0][ks], c0, 0, 0, 0);
    c1 = __builtin_amdgcn_mfma_f32_32x32x16_bf16(a[ks], b[1][ks], c1, 0, 0, 0);
  }
}

// stage one 128x64 half-tile: 512 threads x 2 x 16B
__device__ __forceinline__ void stage2(const unsigned short* s, char* d) {
  gload_lds16(s, d);
  gload_lds16(s + 16384, d + 1024);   // +8 rows
}

__global__ __launch_bounds__(512, 2) void gemm_lse(
    const unsigned short* __restrict__ A,
    const unsigned short* __restrict__ B,
    const int* __restrict__ labels,
    float2* __restrict__ partials,
    float* __restrict__ label_logit) {
  // XCD-aware swizzle: 2000 blocks, 2000%8==0 -> bijective simple form.
  int bid = blockIdx.x;
  int swz = (bid & 7) * 250 + (bid >> 3);
  const int m0 = (swz & 15) * 256;      // 16 mtiles (fast: A panels cycle in L2)
  const int vtile = swz >> 4;           // 0..124
  const int n0 = vtile * 256;

  const int tid = threadIdx.x;
  const int lane = tid & 63;
  const int w = tid >> 6;
  const int wm = w >> 2, wn = w & 3;    // 2x4 wave grid; wave output 128x64

  __shared__ char smem[131072] __attribute__((aligned(128)));
  char* smemc = smem;

  // ---- staging addresses (lane-linear dest; source map matches LDS layout) ----
  const int lane7 = lane & 7, laneC = lane >> 3;
  const unsigned short* Ag = A + (size_t)(m0 + w * 16 + lane7) * 2048 + laneC * 8;
  const unsigned short* Bg = B + (size_t)(n0 + w * 16 + lane7) * 2048 + laneC * 8;
  char* dA = smemc + w * 2048 + lane * 16;
  char* dB = dA + 32768;

  // ---- ds_read bases ----
  const int laneterm = ((lane >> 3) & 3) * 1024 + (lane >> 5) * 128 + (lane & 7) * 16;
  const char* pA0 = smemc + wm * 16384 + laneterm;
  const char* pB0 = smemc + 32768 + wn * 8192 + laneterm;
  const char* pA1 = pA0 + 65536;
  const char* pB1 = pB0 + 65536;

  bf16x8 bfr[2][4], af0[4], af1[4], af2[4], af3[4];
  f32x16 acc[4][2] = {};

  // ---- prologue: buf0 <- kt0 (4 halves), buf1 <- kt1 (B-lo,B-hi,A-lo) ----
  stage2(Bg,                 dB);
  stage2(Bg + 262144,        dB + 16384);
  stage2(Ag,                 dA);
  stage2(Ag + 262144,        dA + 16384);
  stage2(Bg + 64,            dB + 65536);
  stage2(Bg + 262144 + 64,   dB + 65536 + 16384);
  stage2(Ag + 64,            dA + 65536);
  VMCNT(6);                  // buf0's 8 loads done; buf1's 6 in flight
  PH_BARRIER();

#pragma unroll 1
  for (int i = 0; i < 16; ++i) {
    const size_t kt1 = (size_t)(2 * i + 1) * 64;
    const size_t kt2 = (size_t)(2 * i + 2) * 64;
    const size_t kt3 = (size_t)(2 * i + 3) * 64;
    const bool full = (i < 15);

    // ===== K-tile 2i (buf0): phases 1-4 =====
    // P1: read B(8) + A mf0(4); stage buf1.A-hi <- kt1
    ld_b32(bfr, pB0);
    ld_a32(af0, pA0);
    stage2(Ag + 262144 + kt1, dA + 65536 + 16384);
    SCHED_FENCE(); PH_BARRIER(); LGKM0();
    PRIO1(); mfma_ph(acc[0][0], acc[0][1], af0, bfr); PRIO0();
    SCHED_FENCE(); PH_BARRIER();
    // P2: read A mf1(4); stage buf0.B-lo <- kt2 (B regs loaded in P1 -> safe)
    ld_a32(af1, pA0 + 4096);
    if (full) stage2(Bg + kt2, dB);
    SCHED_FENCE(); PH_BARRIER(); LGKM0();
    PRIO1(); mfma_ph(acc[1][0], acc[1][1], af1, bfr); PRIO0();
    SCHED_FENCE(); PH_BARRIER();
    // P3: read A mf2+mf3(8); stage buf0.B-hi <- kt2
    ld_a32(af2, pA0 + 8192);
    ld_a32(af3, pA0 + 12288);
    if (full) stage2(Bg + 262144 + kt2, dB + 16384);
    SCHED_FENCE(); PH_BARRIER(); LGKM0();
    PRIO1(); mfma_ph(acc[2][0], acc[2][1], af2, bfr); PRIO0();
    SCHED_FENCE(); PH_BARRIER();
    // P4: stage buf0.A-lo <- kt2 (all A reads done by P3); counted vmcnt
    if (full) { stage2(Ag + kt2, dA); VMCNT(6); }
    else      { VMCNT(0); }
    SCHED_FENCE(); PH_BARRIER();
    PRIO1(); mfma_ph(acc[3][0], acc[3][1], af3, bfr); PRIO0();
    SCHED_FENCE(); PH_BARRIER();

    // ===== K-tile 2i+1 (buf1): phases 5-8 =====
    // P5: read B(8) + A mf0(4) from buf1; stage buf0.A-hi <- kt2
    ld_b32(bfr, pB1);
    ld_a32(af0, pA1);
    if (full) stage2(Ag + 262144 + kt2, dA + 16384);
    SCHED_FENCE(); PH_BARRIER(); LGKM0();
    PRIO1(); mfma_ph(acc[0][0], acc[0][1], af0, bfr); PRIO0();
    SCHED_FENCE(); PH_BARRIER();
    // P6: read A mf1; stage buf1.B-lo <- kt3
    ld_a32(af1, pA1 + 4096);
    if (full) stage2(Bg + kt3, dB + 65536);
    SCHED_FENCE(); PH_BARRIER(); LGKM0();
    PRIO1(); mfma_ph(acc[1][0], acc[1][1], af1, bfr); PRIO0();
    SCHED_FENCE(); PH_BARRIER();
    // P7: read A mf2+mf3; stage buf1.B-hi <- kt3
    ld_a32(af2, pA1 + 8192);
    ld_a32(af3, pA1 + 12288);
    if (full) stage2(Bg + 262144 + kt3, dB + 65536 + 16384);
    SCHED_FENCE(); PH_BARRIER(); LGKM0();
    PRIO1(); mfma_ph(acc[2][0], acc[2][1], af2, bfr); PRIO0();
    SCHED_FENCE(); PH_BARRIER();
    // P8: stage buf1.A-lo <- kt3; counted vmcnt -> buf0(kt2) ready for next P1
    if (full) { stage2(Ag + kt3, dA + 65536); VMCNT(6); }
    SCHED_FENCE(); PH_BARRIER();
    PRIO1(); mfma_ph(acc[3][0], acc[3][1], af3, bfr); PRIO0();
    SCHED_FENCE(); PH_BARRIER();
  }

  // ---- epilogue: per-row max/sumexp over 256 cols + label pick ----
  __syncthreads();                      // full drain; tile LDS dead -> overlay
  float2* red = (float2*)smemc;         // [4][256] per-wn partials (8KB)
  int* lbl = (int*)(smemc + 8192);      // [256] labels (1KB)
  if (tid < 256) lbl[tid] = labels[m0 + tid];

  // C/D layout 32x32 (m74/m101 verified): col = lane&31,
  // row = (reg&3) + 8*(reg>>2) + 4*(lane>>5)
#pragma unroll
  for (int mf = 0; mf < 4; mf++) {
#pragma unroll
    for (int reg = 0; reg < 16; reg++) {
      float v0 = acc[mf][0][reg], v1 = acc[mf][1][reg];
      float mx = fmaxf(v0, v1);
#pragma unroll
      for (int d = 1; d < 32; d <<= 1) mx = fmaxf(mx, __shfl_xor(mx, d));
      float s = expf(v0 - mx) + expf(v1 - mx);
#pragma unroll
      for (int d = 1; d < 32; d <<= 1) s += __shfl_xor(s, d);
      if ((lane & 31) == 0) {
        int row = wm * 128 + mf * 32 + (reg & 3) + 8 * (reg >> 2) + ((lane >> 5) << 2);
        red[wn * 256 + row] = make_float2(mx, s);
      }
    }
  }
  __syncthreads();

#pragma unroll
  for (int mf = 0; mf < 4; mf++) {
#pragma unroll
    for (int reg = 0; reg < 16; reg++) {
      int row = wm * 128 + mf * 32 + (reg & 3) + 8 * (reg >> 2) + ((lane >> 5) << 2);
      int lb = lbl[row];
#pragma unroll
      for (int nf = 0; nf < 2; nf++) {
        int col = n0 + wn * 64 + nf * 32 + (lane & 31);
        if (lb == col) label_logit[m0 + row] = acc[mf][nf][reg];
      }
    }
  }
  if (tid < 256) {
    float2 p0 = red[tid], p1 = red[256 + tid], p2 = red[512 + tid], p3 = red[768 + tid];
    float M = fmaxf(fmaxf(p0.x, p1.x), fmaxf(p2.x, p3.x));
    float S = p0.y * expf(p0.x - M) + p1.y * expf(p1.x - M) +
              p2.y * expf(p2.x - M) + p3.y * expf(p3.x - M);
    partials[(size_t)(m0 + tid) * 125 + vtile] = make_float2(M, S);
  }
}

// ---------------- one wave per row: combine 125 partials -> row logp ----------------
__global__ void row_lp_k(const float2* __restrict__ parts,   // [2][4096][125]
                         const float* __restrict__ lablog,   // [2][4096]
                         float* __restrict__ rowlp) {        // [2][4096]
  int row = blockIdx.x * 4 + (threadIdx.x >> 6);             // 0..8191
  int lane = threadIdx.x & 63;
  const float2* P = parts + (size_t)row * 125;
  float m = -1e30f, s = 0.f;
  for (int j = lane; j < 125; j += 64) {
    float2 p = P[j];
    if (p.x > m) { s = s * expf(m - p.x) + p.y; m = p.x; }
    else          s += p.y * expf(p.x - m);
  }
#pragma unroll
  for (int d = 1; d < 64; d <<= 1) {
    float om = __shfl_xor(m, d);
    float os = __shfl_xor(s, d);
    float M = fmaxf(m, om);
    s = s * expf(m - M) + os * expf(om - M);
    m = M;
  }
  if (lane == 0) rowlp[row] = lablog[row] - (m + logf(s));
}

// ---------------- per-batch masked mean ----------------
__global__ void reduce_batch_k(const float* __restrict__ rowlp,
                               const int* __restrict__ labels,
                               float* __restrict__ blp) {     // [2][8]
  int path = blockIdx.x >> 3, batch = blockIdx.x & 7;
  int t = threadIdx.x;                                        // 0..511
  int lab = labels[batch * 512 + t];
  float v = rowlp[path * 4096 + batch * 512 + t];
  bool ok = (lab != IGNORE_INDEX);
  float sum = ok ? v : 0.f;
  float cnt = ok ? 1.f : 0.f;
#pragma unroll
  for (int d = 1; d < 64; d <<= 1) { sum += __shfl_xor(sum, d); cnt += __shfl_xor(cnt, d); }
  __shared__ float ws_[8], wc_[8];
  if ((t & 63) == 0) { ws_[t >> 6] = sum; wc_[t >> 6] = cnt; }
  __syncthreads();
  if (t == 0) {
    float S = 0.f, C = 0.f;
    for (int k = 0; k < 8; k++) { S += ws_[k]; C += wc_[k]; }
    blp[blockIdx.x] = (C > 0.f) ? S / C : 0.f;
  }
}

// ---------------- final KTO loss ----------------
__global__ void final_loss(const float* __restrict__ batch_lp, float* __restrict__ out) {
  if (threadIdx.x == 0 && blockIdx.x == 0) {
    float tot = 0.f;
    for (int b = 0; b < 8; b++) {
      float d = batch_lp[b] - batch_lp[8 + b];   // policy - ref
      float z = (b < 4) ? (BETA * d) : (-BETA * d);
      float sg = 1.f / (1.f + expf(-z));
      tot += 1.f - sg;
    }
    out[0] = tot / 8.f;
  }
}

extern "C" void kernel_launch(void* const* d_in, const int* in_sizes, int n_in,
                              void* d_out, int out_size, void* d_ws, size_t ws_size,
                              hipStream_t stream) {
  const float* x     = (const float*)d_in[0];
  const float* ref_x = (const float*)d_in[1];
  const int*   y     = (const int*)d_in[2];
  const float* W     = (const float*)d_in[3];
  const float* ref_W = (const float*)d_in[4];

  // workspace (~173 MB): xb, rxb, Wb (reused per path), partials [2][4096][125],
  // label_logit [2][4096], rowlp [2][4096], batch_lp [2][8]
  unsigned short* xb  = (unsigned short*)d_ws;
  unsigned short* rxb = xb + (size_t)8388608;
  unsigned short* Wb  = rxb + (size_t)8388608;
  char* p2 = (char*)(Wb + (size_t)65536000);
  float2* parts = (float2*)p2;                                   // 8,192,000 B
  float* lablog = (float*)(p2 + (size_t)8192000);                // 32768 B
  float* rowlp  = lablog + 8192;                                 // 32768 B
  float* blp    = rowlp + 8192;                                  // 64 B

  cast_f32_bf16_k<<<4096, 256, 0, stream>>>(x, xb, 8388608LL);
  cast_f32_bf16_k<<<4096, 256, 0, stream>>>(ref_x, rxb, 8388608LL);

  // path 0: policy
  cast_f32_bf16_k<<<32000, 256, 0, stream>>>(W, Wb, 65536000LL);
  gemm_lse<<<2000, 512, 0, stream>>>(xb, Wb, y, parts, lablog);

  // path 1: reference (reuse Wb; stream order serializes)
  cast_f32_bf16_k<<<32000, 256, 0, stream>>>(ref_W, Wb, 65536000LL);
  gemm_lse<<<2000, 512, 0, stream>>>(rxb, Wb, y, parts + (size_t)4096 * 125, lablog + 4096);

  row_lp_k<<<2048, 256, 0, stream>>>(parts, lablog, rowlp);
  reduce_batch_k<<<16, 512, 0, stream>>>(rowlp, y, blp);
  final_loss<<<1, 64, 0, stream>>>(blp, (float*)d_out);
}